// Round 10
// baseline (142.736 us; speedup 1.0000x reference)
//
#include <hip/hip_runtime.h>
#include <stdint.h>

#define BATCH 4
#define NPTS 4096
#define KNN 11            // K+1 neighbors including self
#define LPQ 16            // lanes per query
#define QPB 16            // queries per block
#define CHUNK 1024        // LDS candidate chunk
#define NCHUNK (NPTS / CHUNK)     // 4
#define CPL (CHUNK / LPQ)         // 64 candidates per lane per chunk
#define BUFN 10           // per-lane qualifier buffer slots
#define SENT_BITS 0x433FFFFFFFFFFFFFll

// monotone float -> uint mapping (ascending)
__device__ __forceinline__ unsigned sortable_f32(float d) {
    unsigned b = __float_as_uint(d);
    unsigned m = (unsigned)(((int)b) >> 31) | 0x80000000u;
    return b ^ m;
}

// Fused exact 11-NN + MLP. FROZEN d2 arithmetic (verified r4-r12):
//   sq_j = fl(fl(x2)+fl(y2)) + fl(z2); dot = fma chain; d2 = fl(si+sj)-fl(2t).
// top-k ascending d2, ties -> lower index; key = double with bits
// 0x433<<52 | sortable(d2)<<12 | j  (f64 order == (d2 asc, j asc)).
// r22 = r21 VERBATIM + ONE change: __launch_bounds__(256,2).
// Evidence: every (.,4) build emits ~40B/thread of scratch (WRITE_SIZE
// 10.6MB vs 393KB actual output, byte-identical r20/r21); r14's (256,2)
// build allocated 88 VGPR with WRITE exactly = output (zero spill).
// Occupancy here is LDS-bound (37376B -> 4 blocks/CU = 16 waves/CU needs
// only VGPR <= 128), so relaxing the min-waves bound to 2 (VGPR cap 256)
// lets the allocator keep the kd[11] f64 state in registers at ~88-105
// VGPR -- removing the spill traffic + spill/reload instructions without
// changing residency. Prepass/scan/flush/merge/MLP: untouched.
__global__ __launch_bounds__(256, 2) void fused_kernel(
    const float* __restrict__ pos, const float* __restrict__ vel,
    const float* __restrict__ initc,
    const float* __restrict__ W1, const float* __restrict__ b1,
    const float* __restrict__ W2, const float* __restrict__ b2,
    const float* __restrict__ W3, const float* __restrict__ b3,
    float* __restrict__ out)
{
#pragma clang fp contract(off)
    // skewed float4 (x,y,z,sq): idx + (idx>>6) -> partitions offset by 16B
    __shared__ float4 sp[CHUNK + LPQ];
    // slot-major lane-private buffers: lanes 8B apart -> 2-way -> free
    __shared__ unsigned long long buf[BUFN * 256];

    int b    = blockIdx.x >> 8;           // 256 blocks per batch
    int qblk = blockIdx.x & 255;
    int tid  = threadIdx.x;
    const float* pb = pos + (size_t)b * NPTS * 3;

    int q = tid >> 4, p = tid & 15;
    int i = qblk * QPB + q;               // query index within batch

    float xq = pb[3*i], yq = pb[3*i+1], zq = pb[3*i+2];
    float sqq = xq*xq + yq*yq + zq*zq;    // contract(off): np sum order

    double kd[KNN];
#pragma unroll
    for (int k = 0; k < KNN; ++k) kd[k] = __longlong_as_double(SENT_BITS);
    float tau_f = __builtin_inff();       // conservative gate threshold
    int cnt = 0;

    for (int c = 0; c < NCHUNK; ++c) {
        if (c) __syncthreads();
        for (int j = tid; j < CHUNK; j += 256) {
            int g = c * CHUNK + j;
            float x = pb[3*g], y = pb[3*g+1], z = pb[3*g+2];
            float sq = x*x + y*y + z*z;   // FROZEN staged sq
            sp[j + (j >> 6)] = make_float4(x, y, z, sq);
        }
        __syncthreads();

        int sbase = p * (CPL + 1);
        int jg    = c * CHUNK + p * CPL;

        if (c == 0) {
            // ---- prepass: seed tau from lane-local mins of 32 cands ----
            float mn = __builtin_inff();
            for (int jl = 0; jl < 32; jl += 4) {
                float4 c0 = sp[sbase + jl + 0];
                float4 c1 = sp[sbase + jl + 1];
                float4 c2 = sp[sbase + jl + 2];
                float4 c3 = sp[sbase + jl + 3];
                float t0 = xq*c0.x, t1 = xq*c1.x, t2 = xq*c2.x, t3 = xq*c3.x;
                t0 = fmaf(yq, c0.y, t0); t1 = fmaf(yq, c1.y, t1);
                t2 = fmaf(yq, c2.y, t2); t3 = fmaf(yq, c3.y, t3);
                t0 = fmaf(zq, c0.z, t0); t1 = fmaf(zq, c1.z, t1);
                t2 = fmaf(zq, c2.z, t2); t3 = fmaf(zq, c3.z, t3);
                float d0 = (sqq + c0.w) - 2.0f*t0;
                float d1 = (sqq + c1.w) - 2.0f*t1;
                float d2 = (sqq + c2.w) - 2.0f*t2;
                float d3 = (sqq + c3.w) - 2.0f*t3;
                mn = fminf(mn, fminf(fminf(d0, d1), fminf(d2, d3)));
            }
            // 11-round pop over the 16-lane group -> 11th smallest lane-min
            float mcur = mn, tau = mn;
#pragma unroll
            for (int r = 0; r < KNN; ++r) {
                float h = mcur;
#pragma unroll
                for (int m = 1; m <= 8; m <<= 1)
                    h = fminf(h, __shfl_xor(h, m, LPQ));
                tau = h;
                mcur = (mcur == h) ? __builtin_inff() : mcur;
            }
            tau_f = tau;
        }

        for (int jl = 0; jl < CPL; jl += 4) {
            // 4 back-to-back LDS reads + 4 independent d2 chains (ILP)
            float4 c0 = sp[sbase + jl + 0];
            float4 c1 = sp[sbase + jl + 1];
            float4 c2 = sp[sbase + jl + 2];
            float4 c3 = sp[sbase + jl + 3];
            float t0 = xq*c0.x, t1 = xq*c1.x, t2 = xq*c2.x, t3 = xq*c3.x;
            t0 = fmaf(yq, c0.y, t0); t1 = fmaf(yq, c1.y, t1);
            t2 = fmaf(yq, c2.y, t2); t3 = fmaf(yq, c3.y, t3);
            t0 = fmaf(zq, c0.z, t0); t1 = fmaf(zq, c1.z, t1);
            t2 = fmaf(zq, c2.z, t2); t3 = fmaf(zq, c3.z, t3);
            float d0 = (sqq + c0.w) - 2.0f*t0;
            float d1 = (sqq + c1.w) - 2.0f*t1;
            float d2 = (sqq + c2.w) - 2.0f*t2;
            float d3 = (sqq + c3.w) - 2.0f*t3;

            // f32 gate (== u32 gate by monotonicity); pack only on accept
#pragma unroll
            for (int s = 0; s < 4; ++s) {
                float dv = s == 0 ? d0 : s == 1 ? d1 : s == 2 ? d2 : d3;
                if (dv <= tau_f) {
                    unsigned u  = sortable_f32(dv);
                    unsigned lo = (u << 12) | (unsigned)(jg + jl + s);
                    unsigned hi = 0x43300000u | (u >> 20);
                    buf[cnt * 256 + tid] =
                        ((unsigned long long)hi << 32) | (unsigned long long)lo;
                    ++cnt;
                }
            }

            if (__any(cnt > BUFN - 4)) {
                // ---- flush: drain buffers through the f64 network ----
                for (int k = 0; k < BUFN; ++k) {
                    if (!__any(cnt > k)) break;     // early out
                    unsigned long long kb = buf[k * 256 + tid];
                    double key = (k < cnt) ? __longlong_as_double(kb)
                                           : __longlong_as_double(SENT_BITS);
#pragma unroll
                    for (int kk = KNN-1; kk > 0; --kk) {
                        double mn2 = fmin(kd[kk], key);
                        kd[kk] = fmax(kd[kk-1], mn2);
                    }
                    kd[0] = fmin(kd[0], key);
                }
                cnt = 0;
            }
        }
    }

    // final drain
    for (int k = 0; k < BUFN; ++k) {
        if (!__any(cnt > k)) break;
        unsigned long long kb = buf[k * 256 + tid];
        double key = (k < cnt) ? __longlong_as_double(kb)
                               : __longlong_as_double(SENT_BITS);
#pragma unroll
        for (int kk = KNN-1; kk > 0; --kk) {
            double mn2 = fmin(kd[kk], key);
            kd[kk] = fmax(kd[kk-1], mn2);
        }
        kd[0] = fmin(kd[0], key);
    }

    // destructive 16-lane merge (r8 verbatim) -> res[] = original indices
    unsigned res[KNN];
#pragma unroll
    for (int r = 0; r < KNN; ++r) {
        double h = kd[0];
#pragma unroll
        for (int m = 1; m <= 8; m <<= 1)
            h = fmin(h, __shfl_xor(h, m, LPQ));
        long long hb = __double_as_longlong(h);
        res[r] = (unsigned)(hb & 0xFFF);
        bool own = (__double_as_longlong(kd[0]) == hb);
#pragma unroll
        for (int t = 0; t < KNN-1; ++t) kd[t] = own ? kd[t+1] : kd[t];
        kd[KNN-1] = own ? __longlong_as_double(SENT_BITS) : kd[KNN-1];
    }

    // ---------- fused MLP, lane-parallel, BIT-IDENTICAL to r8 ----------
    const float* vb = vel + (size_t)b * NPTS * 3;

    const float* w0 = W1 + (2*p)   * 66;
    const float* w1 = W1 + (2*p+1) * 66;
    float a0 = b1[2*p], a1 = b1[2*p+1];
#pragma unroll
    for (int k = 1; k < KNN; ++k) {       // ff 0..29: relative positions
        const float* pn = pb + 3*(int)res[k];
        float dx = pn[0] - xq, dy = pn[1] - yq, dz = pn[2] - zq;
        int ff = 3*(k-1);
        a0 = fmaf(dx, w0[ff+0], a0); a1 = fmaf(dx, w1[ff+0], a1);
        a0 = fmaf(dy, w0[ff+1], a0); a1 = fmaf(dy, w1[ff+1], a1);
        a0 = fmaf(dz, w0[ff+2], a0); a1 = fmaf(dz, w1[ff+2], a1);
    }
#pragma unroll
    for (int k = 0; k < KNN; ++k) {       // ff 30..62: velocities
        const float* vn = vb + 3*(int)res[k];
        int ff = 30 + 3*k;
        a0 = fmaf(vn[0], w0[ff+0], a0); a1 = fmaf(vn[0], w1[ff+0], a1);
        a0 = fmaf(vn[1], w0[ff+1], a0); a1 = fmaf(vn[1], w1[ff+1], a1);
        a0 = fmaf(vn[2], w0[ff+2], a0); a1 = fmaf(vn[2], w1[ff+2], a1);
    }
    float c0i = initc[b*3+0], c1i = initc[b*3+1], c2i = initc[b*3+2];
    a0 = fmaf(c0i, w0[63], a0); a1 = fmaf(c0i, w1[63], a1);
    a0 = fmaf(c1i, w0[64], a0); a1 = fmaf(c1i, w1[64], a1);
    a0 = fmaf(c2i, w0[65], a0); a1 = fmaf(c2i, w1[65], a1);

    float h2 = b2[p];
    const float* w2 = W2 + p * 32;
#pragma unroll
    for (int ii = 0; ii < 32; ++ii) {
        float h1v = __shfl((ii & 1) ? a1 : a0, ii >> 1, LPQ);
        h2 = fmaf(h1v, w2[ii], h2);
    }
    int o3 = p < 6 ? p : 0;
    float po = b3[o3];
    const float* w3 = W3 + o3 * 16;
#pragma unroll
    for (int ii = 0; ii < 16; ++ii) {
        float h2v = __shfl(h2, ii, LPQ);
        po = fmaf(h2v, w3[ii], po);
    }
    float resid = (p == 0) ? xq : (p == 1) ? yq : (p == 2) ? zq : 0.0f;
    po += resid;                           // residual on first 3 channels

    if (p < 6)
        out[((size_t)b * NPTS + (size_t)i) * 6 + p] = po;
}

extern "C" void kernel_launch(void* const* d_in, const int* in_sizes, int n_in,
                              void* d_out, int out_size, void* d_ws, size_t ws_size,
                              hipStream_t stream) {
    const float* pos   = (const float*)d_in[0];
    const float* vel   = (const float*)d_in[1];
    const float* initc = (const float*)d_in[2];
    const float* W1    = (const float*)d_in[3];
    const float* b1    = (const float*)d_in[4];
    const float* W2    = (const float*)d_in[5];
    const float* b2    = (const float*)d_in[6];
    const float* W3    = (const float*)d_in[7];
    const float* b3    = (const float*)d_in[8];
    float* out = (float*)d_out;

    fused_kernel<<<dim3(BATCH * (NPTS / QPB)), dim3(256), 0, stream>>>(
        pos, vel, initc, W1, b1, W2, b2, W3, b3, out);
}

// Round 11
// 119.903 us; speedup vs baseline: 1.1904x; 1.1904x over previous
//
#include <hip/hip_runtime.h>
#include <stdint.h>

#define BATCH 4
#define NPTS 4096
#define KNN 11            // K+1 neighbors including self
#define LPQ 16            // lanes per query
#define QPB 16            // queries per block
#define CHUNK 1024        // LDS candidate chunk
#define NCHUNK (NPTS / CHUNK)     // 4
#define CPL (CHUNK / LPQ)         // 64 candidates per lane per chunk
#define BUFN 10           // per-lane qualifier buffer slots
#define SENT_BITS 0x433FFFFFFFFFFFFFll

// monotone float -> uint mapping (ascending)
__device__ __forceinline__ unsigned sortable_f32(float d) {
    unsigned b = __float_as_uint(d);
    unsigned m = (unsigned)(((int)b) >> 31) | 0x80000000u;
    return b ^ m;
}

// Fused exact 11-NN + MLP. FROZEN d2 arithmetic (verified r4-r12):
//   sq_j = fl(fl(x2)+fl(y2)) + fl(z2); dot = fma chain; d2 = fl(si+sj)-fl(2t).
// top-k ascending d2, ties -> lower index; key = double with bits
// 0x433<<52 | sortable(d2)<<12 | j  (f64 order == (d2 asc, j asc)).
// r23 = r21 VERBATIM (62.7us best; r22's lb(256,2) removed the harmless
// off-critical-path spill but regressed codegen 18us -> reverted) + ONE
// change: the prepass scans all 64 chunk-0 candidates per lane (was 32).
// tau = 11th-smallest of 16 lane-mins-of-64: the 11 popped lane-mins are
// actual d2 values of 11 DISTINCT candidates (disjoint lane ranges), all
// <= tau -> true 11th <= tau -> gate conservative -> selection exact.
// Quantile: tau moves ~3.2% -> ~1.6% -> accepts/query ~131 -> ~66 ->
// ~one fewer flush drain (~250 f64-network insts) per lane, for ~192
// cheap pipelined f32 VALU. Scan/flush/merge/MLP: untouched.
__global__ __launch_bounds__(256)
__attribute__((amdgpu_waves_per_eu(4, 4))) void fused_kernel(
    const float* __restrict__ pos, const float* __restrict__ vel,
    const float* __restrict__ initc,
    const float* __restrict__ W1, const float* __restrict__ b1,
    const float* __restrict__ W2, const float* __restrict__ b2,
    const float* __restrict__ W3, const float* __restrict__ b3,
    float* __restrict__ out)
{
#pragma clang fp contract(off)
    // skewed float4 (x,y,z,sq): idx + (idx>>6) -> partitions offset by 16B
    __shared__ float4 sp[CHUNK + LPQ];
    // slot-major lane-private buffers: lanes 8B apart -> 2-way -> free
    __shared__ unsigned long long buf[BUFN * 256];

    int b    = blockIdx.x >> 8;           // 256 blocks per batch
    int qblk = blockIdx.x & 255;
    int tid  = threadIdx.x;
    const float* pb = pos + (size_t)b * NPTS * 3;

    int q = tid >> 4, p = tid & 15;
    int i = qblk * QPB + q;               // query index within batch

    float xq = pb[3*i], yq = pb[3*i+1], zq = pb[3*i+2];
    float sqq = xq*xq + yq*yq + zq*zq;    // contract(off): np sum order

    double kd[KNN];
#pragma unroll
    for (int k = 0; k < KNN; ++k) kd[k] = __longlong_as_double(SENT_BITS);
    float tau_f = __builtin_inff();       // conservative gate threshold
    int cnt = 0;

    for (int c = 0; c < NCHUNK; ++c) {
        if (c) __syncthreads();
        for (int j = tid; j < CHUNK; j += 256) {
            int g = c * CHUNK + j;
            float x = pb[3*g], y = pb[3*g+1], z = pb[3*g+2];
            float sq = x*x + y*y + z*z;   // FROZEN staged sq
            sp[j + (j >> 6)] = make_float4(x, y, z, sq);
        }
        __syncthreads();

        int sbase = p * (CPL + 1);
        int jg    = c * CHUNK + p * CPL;

        if (c == 0) {
            // ---- prepass: seed tau from lane-local mins of all 64 ----
            float mn = __builtin_inff();
            for (int jl = 0; jl < CPL; jl += 4) {
                float4 c0 = sp[sbase + jl + 0];
                float4 c1 = sp[sbase + jl + 1];
                float4 c2 = sp[sbase + jl + 2];
                float4 c3 = sp[sbase + jl + 3];
                float t0 = xq*c0.x, t1 = xq*c1.x, t2 = xq*c2.x, t3 = xq*c3.x;
                t0 = fmaf(yq, c0.y, t0); t1 = fmaf(yq, c1.y, t1);
                t2 = fmaf(yq, c2.y, t2); t3 = fmaf(yq, c3.y, t3);
                t0 = fmaf(zq, c0.z, t0); t1 = fmaf(zq, c1.z, t1);
                t2 = fmaf(zq, c2.z, t2); t3 = fmaf(zq, c3.z, t3);
                float d0 = (sqq + c0.w) - 2.0f*t0;
                float d1 = (sqq + c1.w) - 2.0f*t1;
                float d2 = (sqq + c2.w) - 2.0f*t2;
                float d3 = (sqq + c3.w) - 2.0f*t3;
                mn = fminf(mn, fminf(fminf(d0, d1), fminf(d2, d3)));
            }
            // 11-round pop over the 16-lane group -> 11th smallest lane-min
            float mcur = mn, tau = mn;
#pragma unroll
            for (int r = 0; r < KNN; ++r) {
                float h = mcur;
#pragma unroll
                for (int m = 1; m <= 8; m <<= 1)
                    h = fminf(h, __shfl_xor(h, m, LPQ));
                tau = h;
                mcur = (mcur == h) ? __builtin_inff() : mcur;
            }
            tau_f = tau;
        }

        for (int jl = 0; jl < CPL; jl += 4) {
            // 4 back-to-back LDS reads + 4 independent d2 chains (ILP)
            float4 c0 = sp[sbase + jl + 0];
            float4 c1 = sp[sbase + jl + 1];
            float4 c2 = sp[sbase + jl + 2];
            float4 c3 = sp[sbase + jl + 3];
            float t0 = xq*c0.x, t1 = xq*c1.x, t2 = xq*c2.x, t3 = xq*c3.x;
            t0 = fmaf(yq, c0.y, t0); t1 = fmaf(yq, c1.y, t1);
            t2 = fmaf(yq, c2.y, t2); t3 = fmaf(yq, c3.y, t3);
            t0 = fmaf(zq, c0.z, t0); t1 = fmaf(zq, c1.z, t1);
            t2 = fmaf(zq, c2.z, t2); t3 = fmaf(zq, c3.z, t3);
            float d0 = (sqq + c0.w) - 2.0f*t0;
            float d1 = (sqq + c1.w) - 2.0f*t1;
            float d2 = (sqq + c2.w) - 2.0f*t2;
            float d3 = (sqq + c3.w) - 2.0f*t3;

            // f32 gate (== u32 gate by monotonicity); pack only on accept
#pragma unroll
            for (int s = 0; s < 4; ++s) {
                float dv = s == 0 ? d0 : s == 1 ? d1 : s == 2 ? d2 : d3;
                if (dv <= tau_f) {
                    unsigned u  = sortable_f32(dv);
                    unsigned lo = (u << 12) | (unsigned)(jg + jl + s);
                    unsigned hi = 0x43300000u | (u >> 20);
                    buf[cnt * 256 + tid] =
                        ((unsigned long long)hi << 32) | (unsigned long long)lo;
                    ++cnt;
                }
            }

            if (__any(cnt > BUFN - 4)) {
                // ---- flush: drain buffers through the f64 network ----
                for (int k = 0; k < BUFN; ++k) {
                    if (!__any(cnt > k)) break;     // early out
                    unsigned long long kb = buf[k * 256 + tid];
                    double key = (k < cnt) ? __longlong_as_double(kb)
                                           : __longlong_as_double(SENT_BITS);
#pragma unroll
                    for (int kk = KNN-1; kk > 0; --kk) {
                        double mn2 = fmin(kd[kk], key);
                        kd[kk] = fmax(kd[kk-1], mn2);
                    }
                    kd[0] = fmin(kd[0], key);
                }
                cnt = 0;
            }
        }
    }

    // final drain
    for (int k = 0; k < BUFN; ++k) {
        if (!__any(cnt > k)) break;
        unsigned long long kb = buf[k * 256 + tid];
        double key = (k < cnt) ? __longlong_as_double(kb)
                               : __longlong_as_double(SENT_BITS);
#pragma unroll
        for (int kk = KNN-1; kk > 0; --kk) {
            double mn2 = fmin(kd[kk], key);
            kd[kk] = fmax(kd[kk-1], mn2);
        }
        kd[0] = fmin(kd[0], key);
    }

    // destructive 16-lane merge (r8 verbatim) -> res[] = original indices
    unsigned res[KNN];
#pragma unroll
    for (int r = 0; r < KNN; ++r) {
        double h = kd[0];
#pragma unroll
        for (int m = 1; m <= 8; m <<= 1)
            h = fmin(h, __shfl_xor(h, m, LPQ));
        long long hb = __double_as_longlong(h);
        res[r] = (unsigned)(hb & 0xFFF);
        bool own = (__double_as_longlong(kd[0]) == hb);
#pragma unroll
        for (int t = 0; t < KNN-1; ++t) kd[t] = own ? kd[t+1] : kd[t];
        kd[KNN-1] = own ? __longlong_as_double(SENT_BITS) : kd[KNN-1];
    }

    // ---------- fused MLP, lane-parallel, BIT-IDENTICAL to r8 ----------
    const float* vb = vel + (size_t)b * NPTS * 3;

    const float* w0 = W1 + (2*p)   * 66;
    const float* w1 = W1 + (2*p+1) * 66;
    float a0 = b1[2*p], a1 = b1[2*p+1];
#pragma unroll
    for (int k = 1; k < KNN; ++k) {       // ff 0..29: relative positions
        const float* pn = pb + 3*(int)res[k];
        float dx = pn[0] - xq, dy = pn[1] - yq, dz = pn[2] - zq;
        int ff = 3*(k-1);
        a0 = fmaf(dx, w0[ff+0], a0); a1 = fmaf(dx, w1[ff+0], a1);
        a0 = fmaf(dy, w0[ff+1], a0); a1 = fmaf(dy, w1[ff+1], a1);
        a0 = fmaf(dz, w0[ff+2], a0); a1 = fmaf(dz, w1[ff+2], a1);
    }
#pragma unroll
    for (int k = 0; k < KNN; ++k) {       // ff 30..62: velocities
        const float* vn = vb + 3*(int)res[k];
        int ff = 30 + 3*k;
        a0 = fmaf(vn[0], w0[ff+0], a0); a1 = fmaf(vn[0], w1[ff+0], a1);
        a0 = fmaf(vn[1], w0[ff+1], a0); a1 = fmaf(vn[1], w1[ff+1], a1);
        a0 = fmaf(vn[2], w0[ff+2], a0); a1 = fmaf(vn[2], w1[ff+2], a1);
    }
    float c0i = initc[b*3+0], c1i = initc[b*3+1], c2i = initc[b*3+2];
    a0 = fmaf(c0i, w0[63], a0); a1 = fmaf(c0i, w1[63], a1);
    a0 = fmaf(c1i, w0[64], a0); a1 = fmaf(c1i, w1[64], a1);
    a0 = fmaf(c2i, w0[65], a0); a1 = fmaf(c2i, w1[65], a1);

    float h2 = b2[p];
    const float* w2 = W2 + p * 32;
#pragma unroll
    for (int ii = 0; ii < 32; ++ii) {
        float h1v = __shfl((ii & 1) ? a1 : a0, ii >> 1, LPQ);
        h2 = fmaf(h1v, w2[ii], h2);
    }
    int o3 = p < 6 ? p : 0;
    float po = b3[o3];
    const float* w3 = W3 + o3 * 16;
#pragma unroll
    for (int ii = 0; ii < 16; ++ii) {
        float h2v = __shfl(h2, ii, LPQ);
        po = fmaf(h2v, w3[ii], po);
    }
    float resid = (p == 0) ? xq : (p == 1) ? yq : (p == 2) ? zq : 0.0f;
    po += resid;                           // residual on first 3 channels

    if (p < 6)
        out[((size_t)b * NPTS + (size_t)i) * 6 + p] = po;
}

extern "C" void kernel_launch(void* const* d_in, const int* in_sizes, int n_in,
                              void* d_out, int out_size, void* d_ws, size_t ws_size,
                              hipStream_t stream) {
    const float* pos   = (const float*)d_in[0];
    const float* vel   = (const float*)d_in[1];
    const float* initc = (const float*)d_in[2];
    const float* W1    = (const float*)d_in[3];
    const float* b1    = (const float*)d_in[4];
    const float* W2    = (const float*)d_in[5];
    const float* b2    = (const float*)d_in[6];
    const float* W3    = (const float*)d_in[7];
    const float* b3    = (const float*)d_in[8];
    float* out = (float*)d_out;

    fused_kernel<<<dim3(BATCH * (NPTS / QPB)), dim3(256), 0, stream>>>(
        pos, vel, initc, W1, b1, W2, b2, W3, b3, out);
}

// Round 12
// 117.974 us; speedup vs baseline: 1.2099x; 1.0163x over previous
//
#include <hip/hip_runtime.h>
#include <stdint.h>

#define BATCH 4
#define NPTS 4096
#define KNN 11            // K+1 neighbors including self
#define LPQ 16            // lanes per query
#define QPB 16            // queries per block
#define CHUNK 1024        // LDS candidate chunk
#define NCHUNK (NPTS / CHUNK)     // 4
#define CPL (CHUNK / LPQ)         // 64 candidates per lane per chunk
#define BUFN 10           // per-lane qualifier buffer slots
#define SENT_BITS 0x433FFFFFFFFFFFFFll

// monotone float -> uint mapping (ascending)
__device__ __forceinline__ unsigned sortable_f32(float d) {
    unsigned b = __float_as_uint(d);
    unsigned m = (unsigned)(((int)b) >> 31) | 0x80000000u;
    return b ^ m;
}

// Fused exact 11-NN + MLP. FROZEN d2 arithmetic (verified r4-r12):
//   sq_j = fl(fl(x2)+fl(y2)) + fl(z2); dot = fma chain; d2 = fl(si+sj)-fl(2t).
// top-k ascending d2, ties -> lower index; key = double with bits
// 0x433<<52 | sortable(d2)<<12 | j  (f64 order == (d2 asc, j asc)).
// r24 = r23 VERBATIM (58.8us best) + ONE prepass change: each lane tracks
// its TWO smallest d2 (m1<=m2) over its 64 chunk-0 candidates; the 11-round
// pop then selects the 11th smallest of the 32 tracked values (group-min of
// m1 is the global min since m1<=m2; owner promotes m2). Validity: the 11
// popped values are actual d2's of >=11 DISTINCT (lane,slot) candidates,
// all <= final tau -> true 11th <= tau -> gate conservative -> selection
// exact (ties pop extra values, tau only grows -> still safe). This closes
// the lane-min blind spot (two top-11 in one lane), moving tau from ~1.6%
// to ~1.07% quantile -> accepts ~66 -> ~46/query -> ~30% less pack/flush
// work (r21/r23 proved this region is the most expensive per-inst in the
// kernel). Cost: +2 VALU/cand in prepass + 2 cndmask/round. Scan/flush/
// merge/MLP: untouched.
__global__ __launch_bounds__(256)
__attribute__((amdgpu_waves_per_eu(4, 4))) void fused_kernel(
    const float* __restrict__ pos, const float* __restrict__ vel,
    const float* __restrict__ initc,
    const float* __restrict__ W1, const float* __restrict__ b1,
    const float* __restrict__ W2, const float* __restrict__ b2,
    const float* __restrict__ W3, const float* __restrict__ b3,
    float* __restrict__ out)
{
#pragma clang fp contract(off)
    // skewed float4 (x,y,z,sq): idx + (idx>>6) -> partitions offset by 16B
    __shared__ float4 sp[CHUNK + LPQ];
    // slot-major lane-private buffers: lanes 8B apart -> 2-way -> free
    __shared__ unsigned long long buf[BUFN * 256];

    int b    = blockIdx.x >> 8;           // 256 blocks per batch
    int qblk = blockIdx.x & 255;
    int tid  = threadIdx.x;
    const float* pb = pos + (size_t)b * NPTS * 3;

    int q = tid >> 4, p = tid & 15;
    int i = qblk * QPB + q;               // query index within batch

    float xq = pb[3*i], yq = pb[3*i+1], zq = pb[3*i+2];
    float sqq = xq*xq + yq*yq + zq*zq;    // contract(off): np sum order

    double kd[KNN];
#pragma unroll
    for (int k = 0; k < KNN; ++k) kd[k] = __longlong_as_double(SENT_BITS);
    float tau_f = __builtin_inff();       // conservative gate threshold
    int cnt = 0;

    for (int c = 0; c < NCHUNK; ++c) {
        if (c) __syncthreads();
        for (int j = tid; j < CHUNK; j += 256) {
            int g = c * CHUNK + j;
            float x = pb[3*g], y = pb[3*g+1], z = pb[3*g+2];
            float sq = x*x + y*y + z*z;   // FROZEN staged sq
            sp[j + (j >> 6)] = make_float4(x, y, z, sq);
        }
        __syncthreads();

        int sbase = p * (CPL + 1);
        int jg    = c * CHUNK + p * CPL;

        if (c == 0) {
            // ---- prepass: 2 smallest per lane over all 64 chunk-0 ----
            float m1 = __builtin_inff(), m2 = __builtin_inff();
            for (int jl = 0; jl < CPL; jl += 4) {
                float4 c0 = sp[sbase + jl + 0];
                float4 c1 = sp[sbase + jl + 1];
                float4 c2 = sp[sbase + jl + 2];
                float4 c3 = sp[sbase + jl + 3];
                float t0 = xq*c0.x, t1 = xq*c1.x, t2 = xq*c2.x, t3 = xq*c3.x;
                t0 = fmaf(yq, c0.y, t0); t1 = fmaf(yq, c1.y, t1);
                t2 = fmaf(yq, c2.y, t2); t3 = fmaf(yq, c3.y, t3);
                t0 = fmaf(zq, c0.z, t0); t1 = fmaf(zq, c1.z, t1);
                t2 = fmaf(zq, c2.z, t2); t3 = fmaf(zq, c3.z, t3);
                float d0 = (sqq + c0.w) - 2.0f*t0;
                float d1 = (sqq + c1.w) - 2.0f*t1;
                float d2 = (sqq + c2.w) - 2.0f*t2;
                float d3 = (sqq + c3.w) - 2.0f*t3;
                m2 = fminf(m2, fmaxf(m1, d0)); m1 = fminf(m1, d0);
                m2 = fminf(m2, fmaxf(m1, d1)); m1 = fminf(m1, d1);
                m2 = fminf(m2, fmaxf(m1, d2)); m1 = fminf(m1, d2);
                m2 = fminf(m2, fmaxf(m1, d3)); m1 = fminf(m1, d3);
            }
            // 11-round pop over the 32 tracked values (16 lanes x 2)
            float tau = m1;
#pragma unroll
            for (int r = 0; r < KNN; ++r) {
                float h = m1;
#pragma unroll
                for (int m = 1; m <= 8; m <<= 1)
                    h = fminf(h, __shfl_xor(h, m, LPQ));
                tau = h;
                bool own = (m1 == h);
                m1 = own ? m2 : m1;
                m2 = own ? __builtin_inff() : m2;
            }
            tau_f = tau;
        }

        for (int jl = 0; jl < CPL; jl += 4) {
            // 4 back-to-back LDS reads + 4 independent d2 chains (ILP)
            float4 c0 = sp[sbase + jl + 0];
            float4 c1 = sp[sbase + jl + 1];
            float4 c2 = sp[sbase + jl + 2];
            float4 c3 = sp[sbase + jl + 3];
            float t0 = xq*c0.x, t1 = xq*c1.x, t2 = xq*c2.x, t3 = xq*c3.x;
            t0 = fmaf(yq, c0.y, t0); t1 = fmaf(yq, c1.y, t1);
            t2 = fmaf(yq, c2.y, t2); t3 = fmaf(yq, c3.y, t3);
            t0 = fmaf(zq, c0.z, t0); t1 = fmaf(zq, c1.z, t1);
            t2 = fmaf(zq, c2.z, t2); t3 = fmaf(zq, c3.z, t3);
            float d0 = (sqq + c0.w) - 2.0f*t0;
            float d1 = (sqq + c1.w) - 2.0f*t1;
            float d2 = (sqq + c2.w) - 2.0f*t2;
            float d3 = (sqq + c3.w) - 2.0f*t3;

            // f32 gate (== u32 gate by monotonicity); pack only on accept
#pragma unroll
            for (int s = 0; s < 4; ++s) {
                float dv = s == 0 ? d0 : s == 1 ? d1 : s == 2 ? d2 : d3;
                if (dv <= tau_f) {
                    unsigned u  = sortable_f32(dv);
                    unsigned lo = (u << 12) | (unsigned)(jg + jl + s);
                    unsigned hi = 0x43300000u | (u >> 20);
                    buf[cnt * 256 + tid] =
                        ((unsigned long long)hi << 32) | (unsigned long long)lo;
                    ++cnt;
                }
            }

            if (__any(cnt > BUFN - 4)) {
                // ---- flush: drain buffers through the f64 network ----
                for (int k = 0; k < BUFN; ++k) {
                    if (!__any(cnt > k)) break;     // early out
                    unsigned long long kb = buf[k * 256 + tid];
                    double key = (k < cnt) ? __longlong_as_double(kb)
                                           : __longlong_as_double(SENT_BITS);
#pragma unroll
                    for (int kk = KNN-1; kk > 0; --kk) {
                        double mn2 = fmin(kd[kk], key);
                        kd[kk] = fmax(kd[kk-1], mn2);
                    }
                    kd[0] = fmin(kd[0], key);
                }
                cnt = 0;
            }
        }
    }

    // final drain
    for (int k = 0; k < BUFN; ++k) {
        if (!__any(cnt > k)) break;
        unsigned long long kb = buf[k * 256 + tid];
        double key = (k < cnt) ? __longlong_as_double(kb)
                               : __longlong_as_double(SENT_BITS);
#pragma unroll
        for (int kk = KNN-1; kk > 0; --kk) {
            double mn2 = fmin(kd[kk], key);
            kd[kk] = fmax(kd[kk-1], mn2);
        }
        kd[0] = fmin(kd[0], key);
    }

    // destructive 16-lane merge (r8 verbatim) -> res[] = original indices
    unsigned res[KNN];
#pragma unroll
    for (int r = 0; r < KNN; ++r) {
        double h = kd[0];
#pragma unroll
        for (int m = 1; m <= 8; m <<= 1)
            h = fmin(h, __shfl_xor(h, m, LPQ));
        long long hb = __double_as_longlong(h);
        res[r] = (unsigned)(hb & 0xFFF);
        bool own = (__double_as_longlong(kd[0]) == hb);
#pragma unroll
        for (int t = 0; t < KNN-1; ++t) kd[t] = own ? kd[t+1] : kd[t];
        kd[KNN-1] = own ? __longlong_as_double(SENT_BITS) : kd[KNN-1];
    }

    // ---------- fused MLP, lane-parallel, BIT-IDENTICAL to r8 ----------
    const float* vb = vel + (size_t)b * NPTS * 3;

    const float* w0 = W1 + (2*p)   * 66;
    const float* w1 = W1 + (2*p+1) * 66;
    float a0 = b1[2*p], a1 = b1[2*p+1];
#pragma unroll
    for (int k = 1; k < KNN; ++k) {       // ff 0..29: relative positions
        const float* pn = pb + 3*(int)res[k];
        float dx = pn[0] - xq, dy = pn[1] - yq, dz = pn[2] - zq;
        int ff = 3*(k-1);
        a0 = fmaf(dx, w0[ff+0], a0); a1 = fmaf(dx, w1[ff+0], a1);
        a0 = fmaf(dy, w0[ff+1], a0); a1 = fmaf(dy, w1[ff+1], a1);
        a0 = fmaf(dz, w0[ff+2], a0); a1 = fmaf(dz, w1[ff+2], a1);
    }
#pragma unroll
    for (int k = 0; k < KNN; ++k) {       // ff 30..62: velocities
        const float* vn = vb + 3*(int)res[k];
        int ff = 30 + 3*k;
        a0 = fmaf(vn[0], w0[ff+0], a0); a1 = fmaf(vn[0], w1[ff+0], a1);
        a0 = fmaf(vn[1], w0[ff+1], a0); a1 = fmaf(vn[1], w1[ff+1], a1);
        a0 = fmaf(vn[2], w0[ff+2], a0); a1 = fmaf(vn[2], w1[ff+2], a1);
    }
    float c0i = initc[b*3+0], c1i = initc[b*3+1], c2i = initc[b*3+2];
    a0 = fmaf(c0i, w0[63], a0); a1 = fmaf(c0i, w1[63], a1);
    a0 = fmaf(c1i, w0[64], a0); a1 = fmaf(c1i, w1[64], a1);
    a0 = fmaf(c2i, w0[65], a0); a1 = fmaf(c2i, w1[65], a1);

    float h2 = b2[p];
    const float* w2 = W2 + p * 32;
#pragma unroll
    for (int ii = 0; ii < 32; ++ii) {
        float h1v = __shfl((ii & 1) ? a1 : a0, ii >> 1, LPQ);
        h2 = fmaf(h1v, w2[ii], h2);
    }
    int o3 = p < 6 ? p : 0;
    float po = b3[o3];
    const float* w3 = W3 + o3 * 16;
#pragma unroll
    for (int ii = 0; ii < 16; ++ii) {
        float h2v = __shfl(h2, ii, LPQ);
        po = fmaf(h2v, w3[ii], po);
    }
    float resid = (p == 0) ? xq : (p == 1) ? yq : (p == 2) ? zq : 0.0f;
    po += resid;                           // residual on first 3 channels

    if (p < 6)
        out[((size_t)b * NPTS + (size_t)i) * 6 + p] = po;
}

extern "C" void kernel_launch(void* const* d_in, const int* in_sizes, int n_in,
                              void* d_out, int out_size, void* d_ws, size_t ws_size,
                              hipStream_t stream) {
    const float* pos   = (const float*)d_in[0];
    const float* vel   = (const float*)d_in[1];
    const float* initc = (const float*)d_in[2];
    const float* W1    = (const float*)d_in[3];
    const float* b1    = (const float*)d_in[4];
    const float* W2    = (const float*)d_in[5];
    const float* b2    = (const float*)d_in[6];
    const float* W3    = (const float*)d_in[7];
    const float* b3    = (const float*)d_in[8];
    float* out = (float*)d_out;

    fused_kernel<<<dim3(BATCH * (NPTS / QPB)), dim3(256), 0, stream>>>(
        pos, vel, initc, W1, b1, W2, b2, W3, b3, out);
}

// Round 13
// 117.024 us; speedup vs baseline: 1.2197x; 1.0081x over previous
//
#include <hip/hip_runtime.h>
#include <stdint.h>

#define BATCH 4
#define NPTS 4096
#define KNN 11            // K+1 neighbors including self
#define LPQ 16            // lanes per query
#define QPB 16            // queries per block
#define CHUNK 1024        // LDS candidate chunk
#define NCHUNK (NPTS / CHUNK)     // 4
#define CPL (CHUNK / LPQ)         // 64 candidates per lane per chunk
#define BUFN 10           // per-lane qualifier buffer slots
#define SENT_BITS 0x433FFFFFFFFFFFFFll

// monotone float -> uint mapping (ascending)
__device__ __forceinline__ unsigned sortable_f32(float d) {
    unsigned b = __float_as_uint(d);
    unsigned m = (unsigned)(((int)b) >> 31) | 0x80000000u;
    return b ^ m;
}

// Fused exact 11-NN + MLP. FROZEN d2 arithmetic (verified r4-r12):
//   sq_j = fl(fl(x2)+fl(y2)) + fl(z2); dot = fma chain; d2 = fl(si+sj)-fl(2t)
//   (computed as fmaf(-2,t,sqq+sqj): bit-identical since 2t is exact;
//    verified passing r15-r19; dropped accidentally in r20's revert).
// top-k ascending d2, ties -> lower index; key = double with bits
// 0x433<<52 | sortable(d2)<<12 | j  (f64 order == (d2 asc, j asc)).
// r25 = r24 (54.4us best) + (1) fmaf form restored in prepass+scan and
// (2) ONE mid-scan tau refresh at end of chunk 1: force-drain the pending
// buffer, then an 11-round 2-deep f64 pop over (kd[0],kd[1]) across the 16
// lanes (same structure as the r24 prepass pop, on accumulated keys).
// Validity: prepass guarantees >=11 chunk-0 accepts (the 11 popped
// witnesses -- prepass d2 is bit-identical to scan d2), and the force-drain
// puts them in kd; the popped 11th key >= running 11th >= final 11th ->
// extracted tau >= final 11th d2 -> gate conservative -> selection exact.
// Effect: tau quantile 1.07% -> ~0.54% for chunks 2-3 (accepts ~46 -> ~33;
// r21/r23/r24 measured ~0.1-0.2us per accept). Outer-loop placement only;
// the scan inner loop (codegen-load-bearing, r15/r18) is untouched.
__global__ __launch_bounds__(256)
__attribute__((amdgpu_waves_per_eu(4, 4))) void fused_kernel(
    const float* __restrict__ pos, const float* __restrict__ vel,
    const float* __restrict__ initc,
    const float* __restrict__ W1, const float* __restrict__ b1,
    const float* __restrict__ W2, const float* __restrict__ b2,
    const float* __restrict__ W3, const float* __restrict__ b3,
    float* __restrict__ out)
{
#pragma clang fp contract(off)
    // skewed float4 (x,y,z,sq): idx + (idx>>6) -> partitions offset by 16B
    __shared__ float4 sp[CHUNK + LPQ];
    // slot-major lane-private buffers: lanes 8B apart -> 2-way -> free
    __shared__ unsigned long long buf[BUFN * 256];

    int b    = blockIdx.x >> 8;           // 256 blocks per batch
    int qblk = blockIdx.x & 255;
    int tid  = threadIdx.x;
    const float* pb = pos + (size_t)b * NPTS * 3;

    int q = tid >> 4, p = tid & 15;
    int i = qblk * QPB + q;               // query index within batch

    float xq = pb[3*i], yq = pb[3*i+1], zq = pb[3*i+2];
    float sqq = xq*xq + yq*yq + zq*zq;    // contract(off): np sum order

    double kd[KNN];
#pragma unroll
    for (int k = 0; k < KNN; ++k) kd[k] = __longlong_as_double(SENT_BITS);
    float tau_f = __builtin_inff();       // conservative gate threshold
    int cnt = 0;

    for (int c = 0; c < NCHUNK; ++c) {
        if (c) __syncthreads();
        for (int j = tid; j < CHUNK; j += 256) {
            int g = c * CHUNK + j;
            float x = pb[3*g], y = pb[3*g+1], z = pb[3*g+2];
            float sq = x*x + y*y + z*z;   // FROZEN staged sq
            sp[j + (j >> 6)] = make_float4(x, y, z, sq);
        }
        __syncthreads();

        int sbase = p * (CPL + 1);
        int jg    = c * CHUNK + p * CPL;

        if (c == 0) {
            // ---- prepass: 2 smallest per lane over all 64 chunk-0 ----
            float m1 = __builtin_inff(), m2 = __builtin_inff();
            for (int jl = 0; jl < CPL; jl += 4) {
                float4 c0 = sp[sbase + jl + 0];
                float4 c1 = sp[sbase + jl + 1];
                float4 c2 = sp[sbase + jl + 2];
                float4 c3 = sp[sbase + jl + 3];
                float t0 = xq*c0.x, t1 = xq*c1.x, t2 = xq*c2.x, t3 = xq*c3.x;
                t0 = fmaf(yq, c0.y, t0); t1 = fmaf(yq, c1.y, t1);
                t2 = fmaf(yq, c2.y, t2); t3 = fmaf(yq, c3.y, t3);
                t0 = fmaf(zq, c0.z, t0); t1 = fmaf(zq, c1.z, t1);
                t2 = fmaf(zq, c2.z, t2); t3 = fmaf(zq, c3.z, t3);
                float d0 = fmaf(-2.0f, t0, sqq + c0.w);
                float d1 = fmaf(-2.0f, t1, sqq + c1.w);
                float d2 = fmaf(-2.0f, t2, sqq + c2.w);
                float d3 = fmaf(-2.0f, t3, sqq + c3.w);
                m2 = fminf(m2, fmaxf(m1, d0)); m1 = fminf(m1, d0);
                m2 = fminf(m2, fmaxf(m1, d1)); m1 = fminf(m1, d1);
                m2 = fminf(m2, fmaxf(m1, d2)); m1 = fminf(m1, d2);
                m2 = fminf(m2, fmaxf(m1, d3)); m1 = fminf(m1, d3);
            }
            // 11-round pop over the 32 tracked values (16 lanes x 2)
            float tau = m1;
#pragma unroll
            for (int r = 0; r < KNN; ++r) {
                float h = m1;
#pragma unroll
                for (int m = 1; m <= 8; m <<= 1)
                    h = fminf(h, __shfl_xor(h, m, LPQ));
                tau = h;
                bool own = (m1 == h);
                m1 = own ? m2 : m1;
                m2 = own ? __builtin_inff() : m2;
            }
            tau_f = tau;
        }

        for (int jl = 0; jl < CPL; jl += 4) {
            // 4 back-to-back LDS reads + 4 independent d2 chains (ILP)
            float4 c0 = sp[sbase + jl + 0];
            float4 c1 = sp[sbase + jl + 1];
            float4 c2 = sp[sbase + jl + 2];
            float4 c3 = sp[sbase + jl + 3];
            float t0 = xq*c0.x, t1 = xq*c1.x, t2 = xq*c2.x, t3 = xq*c3.x;
            t0 = fmaf(yq, c0.y, t0); t1 = fmaf(yq, c1.y, t1);
            t2 = fmaf(yq, c2.y, t2); t3 = fmaf(yq, c3.y, t3);
            t0 = fmaf(zq, c0.z, t0); t1 = fmaf(zq, c1.z, t1);
            t2 = fmaf(zq, c2.z, t2); t3 = fmaf(zq, c3.z, t3);
            float d0 = fmaf(-2.0f, t0, sqq + c0.w);
            float d1 = fmaf(-2.0f, t1, sqq + c1.w);
            float d2 = fmaf(-2.0f, t2, sqq + c2.w);
            float d3 = fmaf(-2.0f, t3, sqq + c3.w);

            // f32 gate (== u32 gate by monotonicity); pack only on accept
#pragma unroll
            for (int s = 0; s < 4; ++s) {
                float dv = s == 0 ? d0 : s == 1 ? d1 : s == 2 ? d2 : d3;
                if (dv <= tau_f) {
                    unsigned u  = sortable_f32(dv);
                    unsigned lo = (u << 12) | (unsigned)(jg + jl + s);
                    unsigned hi = 0x43300000u | (u >> 20);
                    buf[cnt * 256 + tid] =
                        ((unsigned long long)hi << 32) | (unsigned long long)lo;
                    ++cnt;
                }
            }

            if (__any(cnt > BUFN - 4)) {
                // ---- flush: drain buffers through the f64 network ----
                for (int k = 0; k < BUFN; ++k) {
                    if (!__any(cnt > k)) break;     // early out
                    unsigned long long kb = buf[k * 256 + tid];
                    double key = (k < cnt) ? __longlong_as_double(kb)
                                           : __longlong_as_double(SENT_BITS);
#pragma unroll
                    for (int kk = KNN-1; kk > 0; --kk) {
                        double mn2 = fmin(kd[kk], key);
                        kd[kk] = fmax(kd[kk-1], mn2);
                    }
                    kd[0] = fmin(kd[0], key);
                }
                cnt = 0;
            }
        }

        if (c == 1) {
            // ---- mid-scan tau refresh from accumulated kd state ----
            // force-drain pending buffer so kd covers all seen accepts
            for (int k = 0; k < BUFN; ++k) {
                if (!__any(cnt > k)) break;
                unsigned long long kb = buf[k * 256 + tid];
                double key = (k < cnt) ? __longlong_as_double(kb)
                                       : __longlong_as_double(SENT_BITS);
#pragma unroll
                for (int kk = KNN-1; kk > 0; --kk) {
                    double mn2 = fmin(kd[kk], key);
                    kd[kk] = fmax(kd[kk-1], mn2);
                }
                kd[0] = fmin(kd[0], key);
            }
            cnt = 0;
            // 2-deep f64 pop over (kd[0],kd[1]) -> 11th of 32 tracked keys
            // >= running 11th >= final 11th -> conservative (>=11 real keys
            // guaranteed: the 11 prepass witnesses were accepted+drained)
            double m1d = kd[0], m2d = kd[1];
            double hpop = m1d;
#pragma unroll
            for (int r = 0; r < KNN; ++r) {
                double h = m1d;
#pragma unroll
                for (int m = 1; m <= 8; m <<= 1)
                    h = fmin(h, __shfl_xor(h, m, LPQ));
                hpop = h;
                bool own = (__double_as_longlong(m1d) ==
                            __double_as_longlong(h));
                m1d = own ? m2d : m1d;
                m2d = own ? __longlong_as_double(SENT_BITS) : m2d;
            }
            unsigned tau_u = (unsigned)((unsigned long long)
                                        __double_as_longlong(hpop) >> 12);
            // unsortable: real d2 keys have top bit set (r13-verified)
            tau_f = __uint_as_float(tau_u ^ 0x80000000u);
        }
    }

    // final drain
    for (int k = 0; k < BUFN; ++k) {
        if (!__any(cnt > k)) break;
        unsigned long long kb = buf[k * 256 + tid];
        double key = (k < cnt) ? __longlong_as_double(kb)
                               : __longlong_as_double(SENT_BITS);
#pragma unroll
        for (int kk = KNN-1; kk > 0; --kk) {
            double mn2 = fmin(kd[kk], key);
            kd[kk] = fmax(kd[kk-1], mn2);
        }
        kd[0] = fmin(kd[0], key);
    }

    // destructive 16-lane merge (r8 verbatim) -> res[] = original indices
    unsigned res[KNN];
#pragma unroll
    for (int r = 0; r < KNN; ++r) {
        double h = kd[0];
#pragma unroll
        for (int m = 1; m <= 8; m <<= 1)
            h = fmin(h, __shfl_xor(h, m, LPQ));
        long long hb = __double_as_longlong(h);
        res[r] = (unsigned)(hb & 0xFFF);
        bool own = (__double_as_longlong(kd[0]) == hb);
#pragma unroll
        for (int t = 0; t < KNN-1; ++t) kd[t] = own ? kd[t+1] : kd[t];
        kd[KNN-1] = own ? __longlong_as_double(SENT_BITS) : kd[KNN-1];
    }

    // ---------- fused MLP, lane-parallel, BIT-IDENTICAL to r8 ----------
    const float* vb = vel + (size_t)b * NPTS * 3;

    const float* w0 = W1 + (2*p)   * 66;
    const float* w1 = W1 + (2*p+1) * 66;
    float a0 = b1[2*p], a1 = b1[2*p+1];
#pragma unroll
    for (int k = 1; k < KNN; ++k) {       // ff 0..29: relative positions
        const float* pn = pb + 3*(int)res[k];
        float dx = pn[0] - xq, dy = pn[1] - yq, dz = pn[2] - zq;
        int ff = 3*(k-1);
        a0 = fmaf(dx, w0[ff+0], a0); a1 = fmaf(dx, w1[ff+0], a1);
        a0 = fmaf(dy, w0[ff+1], a0); a1 = fmaf(dy, w1[ff+1], a1);
        a0 = fmaf(dz, w0[ff+2], a0); a1 = fmaf(dz, w1[ff+2], a1);
    }
#pragma unroll
    for (int k = 0; k < KNN; ++k) {       // ff 30..62: velocities
        const float* vn = vb + 3*(int)res[k];
        int ff = 30 + 3*k;
        a0 = fmaf(vn[0], w0[ff+0], a0); a1 = fmaf(vn[0], w1[ff+0], a1);
        a0 = fmaf(vn[1], w0[ff+1], a0); a1 = fmaf(vn[1], w1[ff+1], a1);
        a0 = fmaf(vn[2], w0[ff+2], a0); a1 = fmaf(vn[2], w1[ff+2], a1);
    }
    float c0i = initc[b*3+0], c1i = initc[b*3+1], c2i = initc[b*3+2];
    a0 = fmaf(c0i, w0[63], a0); a1 = fmaf(c0i, w1[63], a1);
    a0 = fmaf(c1i, w0[64], a0); a1 = fmaf(c1i, w1[64], a1);
    a0 = fmaf(c2i, w0[65], a0); a1 = fmaf(c2i, w1[65], a1);

    float h2 = b2[p];
    const float* w2 = W2 + p * 32;
#pragma unroll
    for (int ii = 0; ii < 32; ++ii) {
        float h1v = __shfl((ii & 1) ? a1 : a0, ii >> 1, LPQ);
        h2 = fmaf(h1v, w2[ii], h2);
    }
    int o3 = p < 6 ? p : 0;
    float po = b3[o3];
    const float* w3 = W3 + o3 * 16;
#pragma unroll
    for (int ii = 0; ii < 16; ++ii) {
        float h2v = __shfl(h2, ii, LPQ);
        po = fmaf(h2v, w3[ii], po);
    }
    float resid = (p == 0) ? xq : (p == 1) ? yq : (p == 2) ? zq : 0.0f;
    po += resid;                           // residual on first 3 channels

    if (p < 6)
        out[((size_t)b * NPTS + (size_t)i) * 6 + p] = po;
}

extern "C" void kernel_launch(void* const* d_in, const int* in_sizes, int n_in,
                              void* d_out, int out_size, void* d_ws, size_t ws_size,
                              hipStream_t stream) {
    const float* pos   = (const float*)d_in[0];
    const float* vel   = (const float*)d_in[1];
    const float* initc = (const float*)d_in[2];
    const float* W1    = (const float*)d_in[3];
    const float* b1    = (const float*)d_in[4];
    const float* W2    = (const float*)d_in[5];
    const float* b2    = (const float*)d_in[6];
    const float* W3    = (const float*)d_in[7];
    const float* b3    = (const float*)d_in[8];
    float* out = (float*)d_out;

    fused_kernel<<<dim3(BATCH * (NPTS / QPB)), dim3(256), 0, stream>>>(
        pos, vel, initc, W1, b1, W2, b2, W3, b3, out);
}

// Round 14
// 116.402 us; speedup vs baseline: 1.2262x; 1.0053x over previous
//
#include <hip/hip_runtime.h>
#include <stdint.h>

#define BATCH 4
#define NPTS 4096
#define KNN 11            // K+1 neighbors including self
#define LPQ 16            // lanes per query
#define QPB 16            // queries per block
#define CHUNK 1024        // LDS candidate chunk
#define NCHUNK (NPTS / CHUNK)     // 4
#define CPL (CHUNK / LPQ)         // 64 candidates per lane per chunk
#define BUFN 10           // per-lane qualifier buffer slots
#define SENT_BITS 0x433FFFFFFFFFFFFFll

// monotone float -> uint mapping (ascending)
__device__ __forceinline__ unsigned sortable_f32(float d) {
    unsigned b = __float_as_uint(d);
    unsigned m = (unsigned)(((int)b) >> 31) | 0x80000000u;
    return b ^ m;
}

// Fused exact 11-NN + MLP. FROZEN d2 arithmetic (verified r4-r12):
//   sq_j = fl(fl(x2)+fl(y2)) + fl(z2); dot = fma chain; d2 = fl(si+sj)-fl(2t)
//   (computed as fmaf(-2,t,sqq+sqj): bit-identical since 2t is exact;
//    verified passing r15-r19, r25).
// top-k ascending d2, ties -> lower index; key = double with bits
// 0x433<<52 | sortable(d2)<<12 | j  (f64 order == (d2 asc, j asc)).
// r26 = r24 structure (measured-best dispatch config, 54.4us) + the fmaf
// d2 form in prepass+scan; r25's mid-scan tau refresh DELETED (isolated as
// a ~2us dispatch regression: its force-drain + 55 dependent f64 shuffles
// outweigh the marginal accept reduction 46->33 -- the tau axis is
// saturated after r21/r23/r24). Prepass: each lane tracks its TWO smallest
// d2 (m1<=m2) over its 64 chunk-0 candidates; 11-round pop over the 32
// tracked values yields tau >= true 11th d2 (11 popped values are actual
// d2's of >=11 distinct candidates, all <= tau) -> gate conservative ->
// selection exact. Scan/flush/merge/MLP: r13-verified verbatim.
__global__ __launch_bounds__(256)
__attribute__((amdgpu_waves_per_eu(4, 4))) void fused_kernel(
    const float* __restrict__ pos, const float* __restrict__ vel,
    const float* __restrict__ initc,
    const float* __restrict__ W1, const float* __restrict__ b1,
    const float* __restrict__ W2, const float* __restrict__ b2,
    const float* __restrict__ W3, const float* __restrict__ b3,
    float* __restrict__ out)
{
#pragma clang fp contract(off)
    // skewed float4 (x,y,z,sq): idx + (idx>>6) -> partitions offset by 16B
    __shared__ float4 sp[CHUNK + LPQ];
    // slot-major lane-private buffers: lanes 8B apart -> 2-way -> free
    __shared__ unsigned long long buf[BUFN * 256];

    int b    = blockIdx.x >> 8;           // 256 blocks per batch
    int qblk = blockIdx.x & 255;
    int tid  = threadIdx.x;
    const float* pb = pos + (size_t)b * NPTS * 3;

    int q = tid >> 4, p = tid & 15;
    int i = qblk * QPB + q;               // query index within batch

    float xq = pb[3*i], yq = pb[3*i+1], zq = pb[3*i+2];
    float sqq = xq*xq + yq*yq + zq*zq;    // contract(off): np sum order

    double kd[KNN];
#pragma unroll
    for (int k = 0; k < KNN; ++k) kd[k] = __longlong_as_double(SENT_BITS);
    float tau_f = __builtin_inff();       // conservative gate threshold
    int cnt = 0;

    for (int c = 0; c < NCHUNK; ++c) {
        if (c) __syncthreads();
        for (int j = tid; j < CHUNK; j += 256) {
            int g = c * CHUNK + j;
            float x = pb[3*g], y = pb[3*g+1], z = pb[3*g+2];
            float sq = x*x + y*y + z*z;   // FROZEN staged sq
            sp[j + (j >> 6)] = make_float4(x, y, z, sq);
        }
        __syncthreads();

        int sbase = p * (CPL + 1);
        int jg    = c * CHUNK + p * CPL;

        if (c == 0) {
            // ---- prepass: 2 smallest per lane over all 64 chunk-0 ----
            float m1 = __builtin_inff(), m2 = __builtin_inff();
            for (int jl = 0; jl < CPL; jl += 4) {
                float4 c0 = sp[sbase + jl + 0];
                float4 c1 = sp[sbase + jl + 1];
                float4 c2 = sp[sbase + jl + 2];
                float4 c3 = sp[sbase + jl + 3];
                float t0 = xq*c0.x, t1 = xq*c1.x, t2 = xq*c2.x, t3 = xq*c3.x;
                t0 = fmaf(yq, c0.y, t0); t1 = fmaf(yq, c1.y, t1);
                t2 = fmaf(yq, c2.y, t2); t3 = fmaf(yq, c3.y, t3);
                t0 = fmaf(zq, c0.z, t0); t1 = fmaf(zq, c1.z, t1);
                t2 = fmaf(zq, c2.z, t2); t3 = fmaf(zq, c3.z, t3);
                float d0 = fmaf(-2.0f, t0, sqq + c0.w);
                float d1 = fmaf(-2.0f, t1, sqq + c1.w);
                float d2 = fmaf(-2.0f, t2, sqq + c2.w);
                float d3 = fmaf(-2.0f, t3, sqq + c3.w);
                m2 = fminf(m2, fmaxf(m1, d0)); m1 = fminf(m1, d0);
                m2 = fminf(m2, fmaxf(m1, d1)); m1 = fminf(m1, d1);
                m2 = fminf(m2, fmaxf(m1, d2)); m1 = fminf(m1, d2);
                m2 = fminf(m2, fmaxf(m1, d3)); m1 = fminf(m1, d3);
            }
            // 11-round pop over the 32 tracked values (16 lanes x 2)
            float tau = m1;
#pragma unroll
            for (int r = 0; r < KNN; ++r) {
                float h = m1;
#pragma unroll
                for (int m = 1; m <= 8; m <<= 1)
                    h = fminf(h, __shfl_xor(h, m, LPQ));
                tau = h;
                bool own = (m1 == h);
                m1 = own ? m2 : m1;
                m2 = own ? __builtin_inff() : m2;
            }
            tau_f = tau;
        }

        for (int jl = 0; jl < CPL; jl += 4) {
            // 4 back-to-back LDS reads + 4 independent d2 chains (ILP)
            float4 c0 = sp[sbase + jl + 0];
            float4 c1 = sp[sbase + jl + 1];
            float4 c2 = sp[sbase + jl + 2];
            float4 c3 = sp[sbase + jl + 3];
            float t0 = xq*c0.x, t1 = xq*c1.x, t2 = xq*c2.x, t3 = xq*c3.x;
            t0 = fmaf(yq, c0.y, t0); t1 = fmaf(yq, c1.y, t1);
            t2 = fmaf(yq, c2.y, t2); t3 = fmaf(yq, c3.y, t3);
            t0 = fmaf(zq, c0.z, t0); t1 = fmaf(zq, c1.z, t1);
            t2 = fmaf(zq, c2.z, t2); t3 = fmaf(zq, c3.z, t3);
            float d0 = fmaf(-2.0f, t0, sqq + c0.w);
            float d1 = fmaf(-2.0f, t1, sqq + c1.w);
            float d2 = fmaf(-2.0f, t2, sqq + c2.w);
            float d3 = fmaf(-2.0f, t3, sqq + c3.w);

            // f32 gate (== u32 gate by monotonicity); pack only on accept
#pragma unroll
            for (int s = 0; s < 4; ++s) {
                float dv = s == 0 ? d0 : s == 1 ? d1 : s == 2 ? d2 : d3;
                if (dv <= tau_f) {
                    unsigned u  = sortable_f32(dv);
                    unsigned lo = (u << 12) | (unsigned)(jg + jl + s);
                    unsigned hi = 0x43300000u | (u >> 20);
                    buf[cnt * 256 + tid] =
                        ((unsigned long long)hi << 32) | (unsigned long long)lo;
                    ++cnt;
                }
            }

            if (__any(cnt > BUFN - 4)) {
                // ---- flush: drain buffers through the f64 network ----
                for (int k = 0; k < BUFN; ++k) {
                    if (!__any(cnt > k)) break;     // early out
                    unsigned long long kb = buf[k * 256 + tid];
                    double key = (k < cnt) ? __longlong_as_double(kb)
                                           : __longlong_as_double(SENT_BITS);
#pragma unroll
                    for (int kk = KNN-1; kk > 0; --kk) {
                        double mn2 = fmin(kd[kk], key);
                        kd[kk] = fmax(kd[kk-1], mn2);
                    }
                    kd[0] = fmin(kd[0], key);
                }
                cnt = 0;
            }
        }
    }

    // final drain
    for (int k = 0; k < BUFN; ++k) {
        if (!__any(cnt > k)) break;
        unsigned long long kb = buf[k * 256 + tid];
        double key = (k < cnt) ? __longlong_as_double(kb)
                               : __longlong_as_double(SENT_BITS);
#pragma unroll
        for (int kk = KNN-1; kk > 0; --kk) {
            double mn2 = fmin(kd[kk], key);
            kd[kk] = fmax(kd[kk-1], mn2);
        }
        kd[0] = fmin(kd[0], key);
    }

    // destructive 16-lane merge (r8 verbatim) -> res[] = original indices
    unsigned res[KNN];
#pragma unroll
    for (int r = 0; r < KNN; ++r) {
        double h = kd[0];
#pragma unroll
        for (int m = 1; m <= 8; m <<= 1)
            h = fmin(h, __shfl_xor(h, m, LPQ));
        long long hb = __double_as_longlong(h);
        res[r] = (unsigned)(hb & 0xFFF);
        bool own = (__double_as_longlong(kd[0]) == hb);
#pragma unroll
        for (int t = 0; t < KNN-1; ++t) kd[t] = own ? kd[t+1] : kd[t];
        kd[KNN-1] = own ? __longlong_as_double(SENT_BITS) : kd[KNN-1];
    }

    // ---------- fused MLP, lane-parallel, BIT-IDENTICAL to r8 ----------
    const float* vb = vel + (size_t)b * NPTS * 3;

    const float* w0 = W1 + (2*p)   * 66;
    const float* w1 = W1 + (2*p+1) * 66;
    float a0 = b1[2*p], a1 = b1[2*p+1];
#pragma unroll
    for (int k = 1; k < KNN; ++k) {       // ff 0..29: relative positions
        const float* pn = pb + 3*(int)res[k];
        float dx = pn[0] - xq, dy = pn[1] - yq, dz = pn[2] - zq;
        int ff = 3*(k-1);
        a0 = fmaf(dx, w0[ff+0], a0); a1 = fmaf(dx, w1[ff+0], a1);
        a0 = fmaf(dy, w0[ff+1], a0); a1 = fmaf(dy, w1[ff+1], a1);
        a0 = fmaf(dz, w0[ff+2], a0); a1 = fmaf(dz, w1[ff+2], a1);
    }
#pragma unroll
    for (int k = 0; k < KNN; ++k) {       // ff 30..62: velocities
        const float* vn = vb + 3*(int)res[k];
        int ff = 30 + 3*k;
        a0 = fmaf(vn[0], w0[ff+0], a0); a1 = fmaf(vn[0], w1[ff+0], a1);
        a0 = fmaf(vn[1], w0[ff+1], a0); a1 = fmaf(vn[1], w1[ff+1], a1);
        a0 = fmaf(vn[2], w0[ff+2], a0); a1 = fmaf(vn[2], w1[ff+2], a1);
    }
    float c0i = initc[b*3+0], c1i = initc[b*3+1], c2i = initc[b*3+2];
    a0 = fmaf(c0i, w0[63], a0); a1 = fmaf(c0i, w1[63], a1);
    a0 = fmaf(c1i, w0[64], a0); a1 = fmaf(c1i, w1[64], a1);
    a0 = fmaf(c2i, w0[65], a0); a1 = fmaf(c2i, w1[65], a1);

    float h2 = b2[p];
    const float* w2 = W2 + p * 32;
#pragma unroll
    for (int ii = 0; ii < 32; ++ii) {
        float h1v = __shfl((ii & 1) ? a1 : a0, ii >> 1, LPQ);
        h2 = fmaf(h1v, w2[ii], h2);
    }
    int o3 = p < 6 ? p : 0;
    float po = b3[o3];
    const float* w3 = W3 + o3 * 16;
#pragma unroll
    for (int ii = 0; ii < 16; ++ii) {
        float h2v = __shfl(h2, ii, LPQ);
        po = fmaf(h2v, w3[ii], po);
    }
    float resid = (p == 0) ? xq : (p == 1) ? yq : (p == 2) ? zq : 0.0f;
    po += resid;                           // residual on first 3 channels

    if (p < 6)
        out[((size_t)b * NPTS + (size_t)i) * 6 + p] = po;
}

extern "C" void kernel_launch(void* const* d_in, const int* in_sizes, int n_in,
                              void* d_out, int out_size, void* d_ws, size_t ws_size,
                              hipStream_t stream) {
    const float* pos   = (const float*)d_in[0];
    const float* vel   = (const float*)d_in[1];
    const float* initc = (const float*)d_in[2];
    const float* W1    = (const float*)d_in[3];
    const float* b1    = (const float*)d_in[4];
    const float* W2    = (const float*)d_in[5];
    const float* b2    = (const float*)d_in[6];
    const float* W3    = (const float*)d_in[7];
    const float* b3    = (const float*)d_in[8];
    float* out = (float*)d_out;

    fused_kernel<<<dim3(BATCH * (NPTS / QPB)), dim3(256), 0, stream>>>(
        pos, vel, initc, W1, b1, W2, b2, W3, b3, out);
}